// Round 4
// baseline (82.905 us; speedup 1.0000x reference)
//
#include <hip/hip_runtime.h>
#include <hip/hip_bf16.h>
#include <stdint.h>

// Galerkin self-attention, fused:
//   out = seq @ (wq.T @ blockdiag_h(kv[b,h]) @ wo.T) + bo
//   kv[b,h] = (1/S) * LN(k)_h^T @ LN(v)_h,   k = seq@wk.T, v = seq@wv.T
// v4: gka_red parallelized (512x256, 8-lane reduce), prep wq transpose via
//     LDS tiles (coalesced), wo converted inline in gka_m1 (wob dropped),
//     gka_out LDS-free (direct global->fragment loads).
// ws layout (bytes):
//   0        wkf bf16 fragment-major [wid][kk][n][lane][8]
//   131072   wvf bf16 fragment-major
//   262144   wqT bf16 [256 i][256 j]
//   393216   (unused)
//   524288   kvf f32 [4 b][4 h][4096 frag]   (fragment order, by gka_red)
//   786432   M1T bf16 [4 b][256 o][256 j]
//   1310720  wcf bf16 fragment-major [b][wid][kk][n][lane][8]
// d_out doubles as scratch for P = bf16 partials [4 b][128 p][4 h][4096 frag]
// (16.8MB of the 33.5MB output buffer); gka_out fully overwrites d_out last.

#define EMBED 256
#define SEQ   8192
#define LN_EPS 1e-5f

using bf16x8 = __attribute__((ext_vector_type(8))) short;
using bf16x4 = __attribute__((ext_vector_type(4))) short;
using f32x4  = __attribute__((ext_vector_type(4))) float;

static __device__ __forceinline__ short f2bf(float f) {
  __hip_bfloat16 h = __float2bfloat16(f);
  return __builtin_bit_cast(short, h);
}
static __device__ __forceinline__ float bf2f(uint32_t u) {
  return __uint_as_float(u << 16);
}

#define MFMA16(a, b, c) __builtin_amdgcn_mfma_f32_16x16x32_bf16((a), (b), (c), 0, 0, 0)

// Stage 64 x 256 fp32 rows -> bf16 LDS [64][256], rows 512B, byte^=(row&7)<<4
static __device__ __forceinline__ void stage_x(char* smem, const float* __restrict__ src, int tid) {
#pragma unroll
  for (int i = 0; i < 8; ++i) {
    int g = tid + i * 256;              // 16B-granule index
    int row = g >> 5, c16 = g & 31;
    const f32x4* p = (const f32x4*)(src + row * EMBED + c16 * 8);
    f32x4 f0 = p[0], f1 = p[1];
    bf16x8 v;
    v[0] = f2bf(f0[0]); v[1] = f2bf(f0[1]); v[2] = f2bf(f0[2]); v[3] = f2bf(f0[3]);
    v[4] = f2bf(f1[0]); v[5] = f2bf(f1[1]); v[6] = f2bf(f1[2]); v[7] = f2bf(f1[3]);
    *(bf16x8*)(smem + row * 512 + ((c16 * 16) ^ ((row & 7) << 4))) = v;
  }
}

// ---------------- prep: wk/wv -> fragment-major bf16; wq -> wqT (tile transpose) -----
__global__ void gka_prep(const float* __restrict__ wq, const float* __restrict__ wk,
                         const float* __restrict__ wv,
                         unsigned short* __restrict__ wkf, unsigned short* __restrict__ wvf,
                         unsigned short* __restrict__ wqt) {
  __shared__ unsigned short T[64 * 66];
  int blk = blockIdx.x, tid = threadIdx.x;
  if (blk < 64) {                         // wk/wv -> fragment-major bf16x8 per thread
    int g = (blk & 31) * 256 + tid;       // [0, 8192)
    const float* W = (blk < 32) ? wk : wv;
    unsigned short* D = (blk < 32) ? wkf : wvf;
    int wid = g >> 11, kk = (g >> 8) & 7, n = (g >> 6) & 3, ln = g & 63;
    int row = wid * 64 + n * 16 + (ln & 15);
    int c0 = kk * 32 + (ln >> 4) * 8;
    const f32x4* p = (const f32x4*)(W + row * 256 + c0);
    f32x4 f0 = p[0], f1 = p[1];
    bf16x8 v;
    v[0] = f2bf(f0[0]); v[1] = f2bf(f0[1]); v[2] = f2bf(f0[2]); v[3] = f2bf(f0[3]);
    v[4] = f2bf(f1[0]); v[5] = f2bf(f1[1]); v[6] = f2bf(f1[2]); v[7] = f2bf(f1[3]);
    *(bf16x8*)(D + g * 8) = v;
    return;
  }
  // 16 blocks: 64x64 tile transpose wqt[i][j] = wq[j][i], coalesced both sides
  int t = blk - 64, ti = t >> 2, tj = t & 3;
#pragma unroll
  for (int it = 0; it < 4; ++it) {
    int g = tid + it * 256;               // 1024 granules of 4 floats
    int jl = g >> 4, g4 = g & 15;
    f32x4 f = *(const f32x4*)(wq + (tj * 64 + jl) * 256 + ti * 64 + g4 * 4);
#pragma unroll
    for (int q = 0; q < 4; ++q) T[jl * 66 + g4 * 4 + q] = (unsigned short)f2bf(f[q]);
  }
  __syncthreads();
#pragma unroll
  for (int it = 0; it < 2; ++it) {
    int g = tid + it * 256;               // 512 output groups of 8
    int il = g >> 3, j8 = g & 7;
    bf16x8 v;
#pragma unroll
    for (int q = 0; q < 8; ++q) v[q] = (short)T[(j8 * 8 + q) * 66 + il];
    *(bf16x8*)(wqt + (ti * 64 + il) * 256 + tj * 64 + j8 * 8) = v;
  }
}

// ---------------- pass A: k,v GEMM + per-head LN + per-tile kv partial ----------------
__global__ __launch_bounds__(256, 2)
void gka_kv(const float* __restrict__ seq,
            const unsigned short* __restrict__ wkf, const unsigned short* __restrict__ wvf,
            const float* __restrict__ lkg, const float* __restrict__ lkb,
            const float* __restrict__ lvg, const float* __restrict__ lvb,
            unsigned short* __restrict__ P) {
  __shared__ char smem[65536];            // [0,32K): x, later vT; [32K,64K): kT
  const int tid = threadIdx.x;
  const int lane = tid & 63;
  const int wid = tid >> 6;               // wave = head
  const int l15 = lane & 15, l4 = lane >> 4, l7 = lane & 7;
  const int tile = blockIdx.x;            // 512 blocks, 64 tokens each
  const int b = tile >> 7;
  const int ptile = tile & 127;

  stage_x(smem, seq + (size_t)(b * SEQ + ptile * 64) * EMBED, tid);
  __syncthreads();

  // two GEMM+LN passes: mat0 = k -> kT @ smem+32K, mat1 = v -> vT @ smem (over x)
#pragma unroll
  for (int mat = 0; mat < 2; ++mat) {
    const unsigned short* Wf = mat ? wvf : wkf;
    const float* gp = mat ? lvg : lkg;
    const float* bp = mat ? lvb : lkb;
    float gv[4], bv[4];
#pragma unroll
    for (int n = 0; n < 4; ++n) { gv[n] = gp[n * 16 + l15]; bv[n] = bp[n * 16 + l15]; }

    f32x4 acc[4][4];
#pragma unroll
    for (int m = 0; m < 4; ++m)
#pragma unroll
      for (int n = 0; n < 4; ++n) acc[m][n] = (f32x4)0.0f;

#pragma unroll
    for (int kk = 0; kk < 8; ++kk) {      // K = 256, steps of 32
      bf16x8 af[4], bw[4];
#pragma unroll
      for (int m = 0; m < 4; ++m) {
        int row = m * 16 + l15;
        af[m] = *(const bf16x8*)(smem + row * 512 + ((kk * 64 + l4 * 16) ^ (l7 << 4)));
      }
#pragma unroll
      for (int n = 0; n < 4; ++n)         // fragment-major: 512B coalesced per wave
        bw[n] = *(const bf16x8*)(Wf + ((((wid * 8 + kk) * 4 + n) * 64 + lane) << 3));
#pragma unroll
      for (int m = 0; m < 4; ++m)
#pragma unroll
        for (int n = 0; n < 4; ++n)
          acc[m][n] = MFMA16(af[m], bw[n], acc[m][n]);
    }

    if (mat == 1) __syncthreads();        // all x-tile reads done; vT may overwrite x

    // LN over this wave's 64 head-cols, write transposed tile straight to LDS
    char* T = smem + (mat ? 0 : 32768) + wid * 8192;   // [64 d|e][64 s] bf16, 128B rows
#pragma unroll
    for (int m = 0; m < 4; ++m) {
      float mu[4], rs[4];
#pragma unroll
      for (int r = 0; r < 4; ++r) {
        float s1 = 0.f, s2 = 0.f;
#pragma unroll
        for (int n = 0; n < 4; ++n) { float x = acc[m][n][r]; s1 += x; s2 += x * x; }
#pragma unroll
        for (int msk = 1; msk < 16; msk <<= 1) {
          s1 += __shfl_xor(s1, msk);
          s2 += __shfl_xor(s2, msk);
        }
        mu[r] = s1 * (1.f / 64.f);
        float var = s2 * (1.f / 64.f) - mu[r] * mu[r];
        rs[r] = rsqrtf(var + LN_EPS);
      }
#pragma unroll
      for (int n = 0; n < 4; ++n) {
        bf16x4 pk;
#pragma unroll
        for (int r = 0; r < 4; ++r)
          pk[r] = f2bf((acc[m][n][r] - mu[r]) * rs[r] * gv[n] + bv[n]);
        int d = n * 16 + l15;             // d&7 == l7
        int sb = m * 32 + l4 * 8;         // byte offset of s0 = m*16+l4*4
        *(bf16x4*)(T + d * 128 + (sb ^ (l7 << 4))) = pk;
      }
    }
  }

  __syncthreads();                        // kT + vT ready

  // kv outer product: wave = head; kv[d][e] += sum_s kT[d][s] * vT[e][s]
  f32x4 a2[4][4];
#pragma unroll
  for (int fd = 0; fd < 4; ++fd)
#pragma unroll
    for (int n = 0; n < 4; ++n) a2[fd][n] = (f32x4)0.0f;

#pragma unroll
  for (int kk = 0; kk < 2; ++kk) {        // 64 tokens = 2 K-steps
    bf16x8 ak[4], bv2[4];
#pragma unroll
    for (int fd = 0; fd < 4; ++fd) {
      int d = fd * 16 + l15;
      ak[fd] = *(const bf16x8*)(smem + 32768 + wid * 8192 + d * 128 +
                                ((kk * 64 + l4 * 16) ^ (l7 << 4)));
    }
#pragma unroll
    for (int n = 0; n < 4; ++n) {
      int e = n * 16 + l15;
      bv2[n] = *(const bf16x8*)(smem + wid * 8192 + e * 128 +
                                ((kk * 64 + l4 * 16) ^ (l7 << 4)));
    }
#pragma unroll
    for (int fd = 0; fd < 4; ++fd)
#pragma unroll
      for (int n = 0; n < 4; ++n)
        a2[fd][n] = MFMA16(ak[fd], bv2[n], a2[fd][n]);
  }

  // store P in raw fragment order: flat = (fd*4+n)*256 + lane*4 + r  (coalesced 512B)
  unsigned short* Ph = P + ((size_t)((b * 128 + ptile) * 4 + wid) << 12);
#pragma unroll
  for (int fd = 0; fd < 4; ++fd)
#pragma unroll
    for (int n = 0; n < 4; ++n) {
      bf16x4 pk;
#pragma unroll
      for (int r = 0; r < 4; ++r) pk[r] = f2bf(a2[fd][n][r]);
      *(bf16x4*)(Ph + (fd * 4 + n) * 256 + lane * 4) = pk;
    }
}

// ---------------- reduce: kvf[b,h,flat] = sum_p P[b,p,h,flat]  (layout-agnostic) -----
__global__ __launch_bounds__(256)
void gka_red(const unsigned short* __restrict__ P, float* __restrict__ kvf) {
  int gtid = blockIdx.x * 256 + threadIdx.x;  // 131072 = 16384 quads x 8 chunks
  int chunk = gtid & 7;
  int qid = gtid >> 3;                        // (b<<12) | (h<<10) | t4
  int b = qid >> 12, h = (qid >> 10) & 3, t4 = qid & 1023;
  const unsigned short* p0 = P + ((size_t)(b * 512 + h) << 12) + t4 * 4;
  float s0 = 0.f, s1 = 0.f, s2 = 0.f, s3 = 0.f;
#pragma unroll
  for (int s = 0; s < 16; ++s) {
    int p = chunk * 16 + s;
    uint2 u = *(const uint2*)(p0 + ((size_t)p << 14));
    s0 += bf2f(u.x & 0xffffu); s1 += bf2f(u.x >> 16);
    s2 += bf2f(u.y & 0xffffu); s3 += bf2f(u.y >> 16);
  }
#pragma unroll
  for (int msk = 1; msk < 8; msk <<= 1) {
    s0 += __shfl_xor(s0, msk); s1 += __shfl_xor(s1, msk);
    s2 += __shfl_xor(s2, msk); s3 += __shfl_xor(s3, msk);
  }
  if (chunk == 0) {
    f32x4 r; r[0] = s0; r[1] = s1; r[2] = s2; r[3] = s3;
    *(f32x4*)(kvf + (qid << 2)) = r;
  }
}

// ---------------- pass B1: M1T[b][o][j=h*64+d] = sum_e kv[d][e]/S * wo[o][h*64+e] ----
__global__ __launch_bounds__(256, 2)
void gka_m1(const float* __restrict__ kvf, const float* __restrict__ wo,
            unsigned short* __restrict__ m1t) {
  const int tid = threadIdx.x;
  const int lane = tid & 63;
  const int wid = tid >> 6;               // wave -> o-range
  const int l15 = lane & 15, l4 = lane >> 4;
  const int blk = blockIdx.x;             // 16 = 4b x 4h
  const int b = blk >> 2, h = blk & 3;
  const float invS = 1.f / (float)SEQ;
  const float* kvh = kvf + ((b * 4 + h) << 12);

  f32x4 acc[4][4];
#pragma unroll
  for (int m = 0; m < 4; ++m)
#pragma unroll
    for (int n = 0; n < 4; ++n) acc[m][n] = (f32x4)0.0f;

#pragma unroll
  for (int kk = 0; kk < 2; ++kk) {        // K = 64 (e)
    bf16x8 af[4], bw[4];
#pragma unroll
    for (int m = 0; m < 4; ++m) {
      // gather (d = m*16+l15, e = kk*32+l4*8+j) from fragment layout
      int base = (m * 4 + kk * 2 + (l4 >> 1)) * 256 +
                 ((l15 >> 2) * 16 + (l4 & 1) * 8) * 4 + (l15 & 3);
      bf16x8 v;
#pragma unroll
      for (int j = 0; j < 8; ++j) v[j] = f2bf(kvh[base + j * 4] * invS);
      af[m] = v;
    }
#pragma unroll
    for (int n = 0; n < 4; ++n) {
      int o = wid * 64 + n * 16 + l15;
      const f32x4* wp = (const f32x4*)(wo + (size_t)o * 256 + h * 64 + kk * 32 + l4 * 8);
      f32x4 w0 = wp[0], w1 = wp[1];
      bf16x8 v;
      v[0] = f2bf(w0[0]); v[1] = f2bf(w0[1]); v[2] = f2bf(w0[2]); v[3] = f2bf(w0[3]);
      v[4] = f2bf(w1[0]); v[5] = f2bf(w1[1]); v[6] = f2bf(w1[2]); v[7] = f2bf(w1[3]);
      bw[n] = v;
    }
#pragma unroll
    for (int m = 0; m < 4; ++m)
#pragma unroll
      for (int n = 0; n < 4; ++n)
        acc[m][n] = MFMA16(af[m], bw[n], acc[m][n]);
  }
#pragma unroll
  for (int m = 0; m < 4; ++m)
#pragma unroll
    for (int n = 0; n < 4; ++n) {
      int o = wid * 64 + n * 16 + l15;
      int j0 = h * 64 + m * 16 + l4 * 4;
      bf16x4 pk;
#pragma unroll
      for (int r = 0; r < 4; ++r) pk[r] = f2bf(acc[m][n][r]);
      *(bf16x4*)(m1t + (size_t)(b * 256 + o) * 256 + j0) = pk;
    }
}

// ---------------- pass B2: wcf = fragment-major WcT; Wc[i][o] = sum_j wqT[i][j]*M1T[o][j]
__global__ __launch_bounds__(512, 2)
void gka_wc(const unsigned short* __restrict__ wqt, const unsigned short* __restrict__ m1t,
            unsigned short* __restrict__ wcf) {
  const int tid = threadIdx.x;
  const int lane = tid & 63;
  const int wid = tid >> 6;               // 8 waves: 2M x 4N
  const int wm = wid >> 2, wn = wid & 3;
  const int l15 = lane & 15, l4 = lane >> 4;
  const int blk = blockIdx.x;             // 8 = 4b x 2 i-half
  const int b = blk >> 1, ih = blk & 1;

  f32x4 acc[4][4];
#pragma unroll
  for (int m = 0; m < 4; ++m)
#pragma unroll
    for (int n = 0; n < 4; ++n) acc[m][n] = (f32x4)0.0f;

#pragma unroll
  for (int kk = 0; kk < 8; ++kk) {        // K = 256 (j)
    bf16x8 af[4], bw[4];
#pragma unroll
    for (int m = 0; m < 4; ++m) {
      int i = ih * 128 + wm * 64 + m * 16 + l15;
      af[m] = *(const bf16x8*)(wqt + i * 256 + kk * 32 + l4 * 8);
    }
#pragma unroll
    for (int n = 0; n < 4; ++n) {
      int o = wn * 64 + n * 16 + l15;
      bw[n] = *(const bf16x8*)(m1t + (size_t)(b * 256 + o) * 256 + kk * 32 + l4 * 8);
    }
#pragma unroll
    for (int m = 0; m < 4; ++m)
#pragma unroll
      for (int n = 0; n < 4; ++n)
        acc[m][n] = MFMA16(af[m], bw[n], acc[m][n]);
  }
  // store to fragment-major wcf for gka_out
#pragma unroll
  for (int m = 0; m < 4; ++m)
#pragma unroll
    for (int n = 0; n < 4; ++n) {
      int kko = ih * 4 + wm * 2 + (m >> 1);
      int laneo = ((m & 1) * 2 + (l4 >> 1)) * 16 + l15;
      int jo = (l4 & 1) * 4;
      bf16x4 pk;
#pragma unroll
      for (int r = 0; r < 4; ++r) pk[r] = f2bf(acc[m][n][r]);
      *(bf16x4*)(wcf + ((size_t)b << 16) +
                 (((((wn * 8 + kko) * 4 + n) * 64) + laneo) << 3) + jo) = pk;
    }
}

// ---------------- pass C: out = seq @ Wc[b] + bo  (LDS-free streaming) ---------------
__global__ __launch_bounds__(256, 4)
void gka_out(const float* __restrict__ seq, const unsigned short* __restrict__ wcf,
             const float* __restrict__ bo, float* __restrict__ out) {
  const int tid = threadIdx.x;
  const int lane = tid & 63;
  const int wid = tid >> 6;               // wave -> o-range (64 cols)
  const int l15 = lane & 15, l4 = lane >> 4;
  const int tile = blockIdx.x;            // 1024 = 4b x 256 tiles of 32 rows
  const int b = tile >> 8;
  const int srow = (tile & 255) * 32;

  const float* X = seq + (size_t)(b * SEQ + srow) * EMBED;
  const unsigned short* Wf = wcf + ((size_t)b << 16);
  float bov[4];
#pragma unroll
  for (int n = 0; n < 4; ++n) bov[n] = bo[wid * 64 + n * 16 + l15];

  f32x4 acc[2][4];
#pragma unroll
  for (int m = 0; m < 2; ++m)
#pragma unroll
    for (int n = 0; n < 4; ++n) acc[m][n] = (f32x4)0.0f;

#pragma unroll
  for (int kk = 0; kk < 8; ++kk) {        // K = 256; A-frags direct from global
    bf16x8 af[2], bw[4];
#pragma unroll
    for (int m = 0; m < 2; ++m) {
      const f32x4* p = (const f32x4*)(X + (m * 16 + l15) * EMBED + kk * 32 + l4 * 8);
      f32x4 f0 = p[0], f1 = p[1];
      bf16x8 v;
      v[0] = f2bf(f0[0]); v[1] = f2bf(f0[1]); v[2] = f2bf(f0[2]); v[3] = f2bf(f0[3]);
      v[4] = f2bf(f1[0]); v[5] = f2bf(f1[1]); v[6] = f2bf(f1[2]); v[7] = f2bf(f1[3]);
      af[m] = v;
    }
#pragma unroll
    for (int n = 0; n < 4; ++n)           // coalesced 512B per wave, L2-resident
      bw[n] = *(const bf16x8*)(Wf + ((((wid * 8 + kk) * 4 + n) * 64 + lane) << 3));
#pragma unroll
    for (int m = 0; m < 2; ++m)
#pragma unroll
      for (int n = 0; n < 4; ++n)
        acc[m][n] = MFMA16(af[m], bw[n], acc[m][n]);
  }

  float* dst = out + (size_t)(b * SEQ + srow) * EMBED;
#pragma unroll
  for (int m = 0; m < 2; ++m)
#pragma unroll
    for (int n = 0; n < 4; ++n)
#pragma unroll
      for (int r = 0; r < 4; ++r)
        dst[(size_t)(m * 16 + l4 * 4 + r) * EMBED + wid * 64 + n * 16 + l15] =
            acc[m][n][r] + bov[n];
}

extern "C" void kernel_launch(void* const* d_in, const int* in_sizes, int n_in,
                              void* d_out, int out_size, void* d_ws, size_t ws_size,
                              hipStream_t stream) {
  const float* seq = (const float*)d_in[0];
  const float* wq  = (const float*)d_in[1];
  const float* wk  = (const float*)d_in[2];
  const float* wv  = (const float*)d_in[3];
  const float* wo  = (const float*)d_in[4];
  const float* bo  = (const float*)d_in[5];
  const float* lkg = (const float*)d_in[6];
  const float* lkb = (const float*)d_in[7];
  const float* lvg = (const float*)d_in[8];
  const float* lvb = (const float*)d_in[9];
  float* out = (float*)d_out;
  char* ws = (char*)d_ws;

  unsigned short* wkf = (unsigned short*)(ws + 0);
  unsigned short* wvf = (unsigned short*)(ws + 131072);
  unsigned short* wqt = (unsigned short*)(ws + 262144);
  float*          kvf = (float*)(ws + 524288);
  unsigned short* m1t = (unsigned short*)(ws + 786432);
  unsigned short* wcf = (unsigned short*)(ws + 1310720);
  unsigned short* P   = (unsigned short*)d_out;   // 16.8MB partials, overwritten by gka_out

  gka_prep<<<80, 256, 0, stream>>>(wq, wk, wv, wkf, wvf, wqt);
  gka_kv<<<512, 256, 0, stream>>>(seq, wkf, wvf, lkg, lkb, lvg, lvb, P);
  gka_red<<<512, 256, 0, stream>>>(P, kvf);
  gka_m1<<<16, 256, 0, stream>>>(kvf, wo, m1t);
  gka_wc<<<8, 512, 0, stream>>>(wqt, m1t, wcf);
  gka_out<<<1024, 256, 0, stream>>>(seq, wcf, bo, out);
}

// Round 5
// 73.500 us; speedup vs baseline: 1.1280x; 1.1280x over previous
//
#include <hip/hip_runtime.h>
#include <hip/hip_bf16.h>
#include <stdint.h>

// Galerkin self-attention, fused:
//   out = seq @ (wq.T @ blockdiag_h(kv[b,h]) @ wo.T) + bo
//   kv[b,h] = (1/S) * LN(k)_h^T @ LN(v)_h,   k = seq@wk.T, v = seq@wv.T
// v5: gka_kv merged k+v K-loop (A-fragment reuse, 2x MFMA ILP);
//     gka_out reverted to LDS-staged (r3) after r4's uncoalesced regression;
//     parallel gka_red + coalesced prep kept from v4.
// ws layout (bytes):
//   0        wkf bf16 fragment-major [wid][kk][n][lane][8]
//   131072   wvf bf16 fragment-major
//   262144   wqT bf16 [256 i][256 j]
//   524288   kvf f32 [4 b][4 h][4096 frag]   (fragment order, by gka_red)
//   786432   M1T bf16 [4 b][256 o][256 j]
//   1310720  wcf bf16 fragment-major [b][wid][kk][n][lane][8]
// d_out doubles as scratch for P = bf16 partials [4 b][128 p][4 h][4096 frag]
// (16.8MB of the 33.5MB output buffer); gka_out fully overwrites d_out last.

#define EMBED 256
#define SEQ   8192
#define LN_EPS 1e-5f

using bf16x8 = __attribute__((ext_vector_type(8))) short;
using bf16x4 = __attribute__((ext_vector_type(4))) short;
using f32x4  = __attribute__((ext_vector_type(4))) float;

static __device__ __forceinline__ short f2bf(float f) {
  __hip_bfloat16 h = __float2bfloat16(f);
  return __builtin_bit_cast(short, h);
}
static __device__ __forceinline__ float bf2f(uint32_t u) {
  return __uint_as_float(u << 16);
}

#define MFMA16(a, b, c) __builtin_amdgcn_mfma_f32_16x16x32_bf16((a), (b), (c), 0, 0, 0)

// Stage ROWS x 256 fp32 rows -> bf16 LDS [ROWS][256], rows 512B, byte^=(row&7)<<4
template <int ROWS>
static __device__ __forceinline__ void stage_x(char* smem, const float* __restrict__ src, int tid) {
#pragma unroll
  for (int i = 0; i < ROWS / 8; ++i) {
    int g = tid + i * 256;              // 16B-granule index
    int row = g >> 5, c16 = g & 31;
    const f32x4* p = (const f32x4*)(src + row * EMBED + c16 * 8);
    f32x4 f0 = p[0], f1 = p[1];
    bf16x8 v;
    v[0] = f2bf(f0[0]); v[1] = f2bf(f0[1]); v[2] = f2bf(f0[2]); v[3] = f2bf(f0[3]);
    v[4] = f2bf(f1[0]); v[5] = f2bf(f1[1]); v[6] = f2bf(f1[2]); v[7] = f2bf(f1[3]);
    *(bf16x8*)(smem + row * 512 + ((c16 * 16) ^ ((row & 7) << 4))) = v;
  }
}

// ---------------- prep: wk/wv -> fragment-major bf16; wq -> wqT (tile transpose) -----
__global__ void gka_prep(const float* __restrict__ wq, const float* __restrict__ wk,
                         const float* __restrict__ wv,
                         unsigned short* __restrict__ wkf, unsigned short* __restrict__ wvf,
                         unsigned short* __restrict__ wqt) {
  __shared__ unsigned short T[64 * 66];
  int blk = blockIdx.x, tid = threadIdx.x;
  if (blk < 64) {                         // wk/wv -> fragment-major bf16x8 per thread
    int g = (blk & 31) * 256 + tid;       // [0, 8192)
    const float* W = (blk < 32) ? wk : wv;
    unsigned short* D = (blk < 32) ? wkf : wvf;
    int wid = g >> 11, kk = (g >> 8) & 7, n = (g >> 6) & 3, ln = g & 63;
    int row = wid * 64 + n * 16 + (ln & 15);
    int c0 = kk * 32 + (ln >> 4) * 8;
    const f32x4* p = (const f32x4*)(W + row * 256 + c0);
    f32x4 f0 = p[0], f1 = p[1];
    bf16x8 v;
    v[0] = f2bf(f0[0]); v[1] = f2bf(f0[1]); v[2] = f2bf(f0[2]); v[3] = f2bf(f0[3]);
    v[4] = f2bf(f1[0]); v[5] = f2bf(f1[1]); v[6] = f2bf(f1[2]); v[7] = f2bf(f1[3]);
    *(bf16x8*)(D + g * 8) = v;
    return;
  }
  // 16 blocks: 64x64 tile transpose wqt[i][j] = wq[j][i], coalesced both sides
  int t = blk - 64, ti = t >> 2, tj = t & 3;
#pragma unroll
  for (int it = 0; it < 4; ++it) {
    int g = tid + it * 256;               // 1024 granules of 4 floats
    int jl = g >> 4, g4 = g & 15;
    f32x4 f = *(const f32x4*)(wq + (tj * 64 + jl) * 256 + ti * 64 + g4 * 4);
#pragma unroll
    for (int q = 0; q < 4; ++q) T[jl * 66 + g4 * 4 + q] = (unsigned short)f2bf(f[q]);
  }
  __syncthreads();
#pragma unroll
  for (int it = 0; it < 2; ++it) {
    int g = tid + it * 256;               // 512 output groups of 8
    int il = g >> 3, j8 = g & 7;
    bf16x8 v;
#pragma unroll
    for (int q = 0; q < 8; ++q) v[q] = (short)T[(j8 * 8 + q) * 66 + il];
    *(bf16x8*)(wqt + (ti * 64 + il) * 256 + tj * 64 + j8 * 8) = v;
  }
}

// ---------------- pass A: k,v GEMM (merged) + per-head LN + per-tile kv partial ------
__global__ __launch_bounds__(256, 2)
void gka_kv(const float* __restrict__ seq,
            const unsigned short* __restrict__ wkf, const unsigned short* __restrict__ wvf,
            const float* __restrict__ lkg, const float* __restrict__ lkb,
            const float* __restrict__ lvg, const float* __restrict__ lvb,
            unsigned short* __restrict__ P) {
  __shared__ char smem[65536];            // [0,32K): x, later vT; [32K,64K): kT
  const int tid = threadIdx.x;
  const int lane = tid & 63;
  const int wid = tid >> 6;               // wave = head
  const int l15 = lane & 15, l4 = lane >> 4, l7 = lane & 7;
  const int tile = blockIdx.x;            // 512 blocks, 64 tokens each
  const int b = tile >> 7;
  const int ptile = tile & 127;

  stage_x<64>(smem, seq + (size_t)(b * SEQ + ptile * 64) * EMBED, tid);
  __syncthreads();

  // merged k+v GEMM: one pass over x, both weight streams
  f32x4 acck[4][4], accv[4][4];
#pragma unroll
  for (int m = 0; m < 4; ++m)
#pragma unroll
    for (int n = 0; n < 4; ++n) { acck[m][n] = (f32x4)0.0f; accv[m][n] = (f32x4)0.0f; }

#pragma unroll
  for (int kk = 0; kk < 8; ++kk) {        // K = 256, steps of 32
    bf16x8 af[4], bwk[4], bwv[4];
#pragma unroll
    for (int m = 0; m < 4; ++m) {
      int row = m * 16 + l15;
      af[m] = *(const bf16x8*)(smem + row * 512 + ((kk * 64 + l4 * 16) ^ (l7 << 4)));
    }
#pragma unroll
    for (int n = 0; n < 4; ++n) {         // fragment-major: 512B coalesced per wave
      size_t off = (((wid * 8 + kk) * 4 + n) * 64 + lane) << 3;
      bwk[n] = *(const bf16x8*)(wkf + off);
      bwv[n] = *(const bf16x8*)(wvf + off);
    }
#pragma unroll
    for (int m = 0; m < 4; ++m)
#pragma unroll
      for (int n = 0; n < 4; ++n) {
        acck[m][n] = MFMA16(af[m], bwk[n], acck[m][n]);
        accv[m][n] = MFMA16(af[m], bwv[n], accv[m][n]);
      }
  }

  __syncthreads();                        // all x-tile LDS reads done

  // LN over this wave's 64 head-cols; write kT -> smem+32K, vT -> smem (over x)
#pragma unroll
  for (int mat = 0; mat < 2; ++mat) {
    const f32x4 (*acc)[4] = mat ? accv : acck;     // mat is unroll-static
    const float* gp = mat ? lvg : lkg;
    const float* bp = mat ? lvb : lkb;
    float gv[4], bv[4];
#pragma unroll
    for (int n = 0; n < 4; ++n) { gv[n] = gp[n * 16 + l15]; bv[n] = bp[n * 16 + l15]; }
    char* T = smem + (mat ? 0 : 32768) + wid * 8192;  // [64 d|e][64 s] bf16, 128B rows
#pragma unroll
    for (int m = 0; m < 4; ++m) {
      float mu[4], rs[4];
#pragma unroll
      for (int r = 0; r < 4; ++r) {
        float s1 = 0.f, s2 = 0.f;
#pragma unroll
        for (int n = 0; n < 4; ++n) { float x = acc[m][n][r]; s1 += x; s2 += x * x; }
#pragma unroll
        for (int msk = 1; msk < 16; msk <<= 1) {
          s1 += __shfl_xor(s1, msk);
          s2 += __shfl_xor(s2, msk);
        }
        mu[r] = s1 * (1.f / 64.f);
        float var = s2 * (1.f / 64.f) - mu[r] * mu[r];
        rs[r] = rsqrtf(var + LN_EPS);
      }
#pragma unroll
      for (int n = 0; n < 4; ++n) {
        bf16x4 pk;
#pragma unroll
        for (int r = 0; r < 4; ++r)
          pk[r] = f2bf((acc[m][n][r] - mu[r]) * rs[r] * gv[n] + bv[n]);
        int d = n * 16 + l15;             // d&7 == l7
        int sb = m * 32 + l4 * 8;         // byte offset of s0 = m*16+l4*4
        *(bf16x4*)(T + d * 128 + (sb ^ (l7 << 4))) = pk;
      }
    }
  }

  __syncthreads();                        // kT + vT ready

  // kv outer product: wave = head; kv[d][e] += sum_s kT[d][s] * vT[e][s]
  f32x4 a2[4][4];
#pragma unroll
  for (int fd = 0; fd < 4; ++fd)
#pragma unroll
    for (int n = 0; n < 4; ++n) a2[fd][n] = (f32x4)0.0f;

#pragma unroll
  for (int kk = 0; kk < 2; ++kk) {        // 64 tokens = 2 K-steps
    bf16x8 ak[4], bv2[4];
#pragma unroll
    for (int fd = 0; fd < 4; ++fd) {
      int d = fd * 16 + l15;
      ak[fd] = *(const bf16x8*)(smem + 32768 + wid * 8192 + d * 128 +
                                ((kk * 64 + l4 * 16) ^ (l7 << 4)));
    }
#pragma unroll
    for (int n = 0; n < 4; ++n) {
      int e = n * 16 + l15;
      bv2[n] = *(const bf16x8*)(smem + wid * 8192 + e * 128 +
                                ((kk * 64 + l4 * 16) ^ (l7 << 4)));
    }
#pragma unroll
    for (int fd = 0; fd < 4; ++fd)
#pragma unroll
      for (int n = 0; n < 4; ++n)
        a2[fd][n] = MFMA16(ak[fd], bv2[n], a2[fd][n]);
  }

  // store P in raw fragment order: flat = (fd*4+n)*256 + lane*4 + r  (coalesced 512B)
  unsigned short* Ph = P + ((size_t)((b * 128 + ptile) * 4 + wid) << 12);
#pragma unroll
  for (int fd = 0; fd < 4; ++fd)
#pragma unroll
    for (int n = 0; n < 4; ++n) {
      bf16x4 pk;
#pragma unroll
      for (int r = 0; r < 4; ++r) pk[r] = f2bf(a2[fd][n][r]);
      *(bf16x4*)(Ph + (fd * 4 + n) * 256 + lane * 4) = pk;
    }
}

// ---------------- reduce: kvf[b,h,flat] = sum_p P[b,p,h,flat]  (layout-agnostic) -----
__global__ __launch_bounds__(256)
void gka_red(const unsigned short* __restrict__ P, float* __restrict__ kvf) {
  int gtid = blockIdx.x * 256 + threadIdx.x;  // 131072 = 16384 quads x 8 chunks
  int chunk = gtid & 7;
  int qid = gtid >> 3;                        // (b<<12) | (h<<10) | t4
  int b = qid >> 12, h = (qid >> 10) & 3, t4 = qid & 1023;
  const unsigned short* p0 = P + ((size_t)(b * 512 + h) << 12) + t4 * 4;
  float s0 = 0.f, s1 = 0.f, s2 = 0.f, s3 = 0.f;
#pragma unroll
  for (int s = 0; s < 16; ++s) {
    int p = chunk * 16 + s;
    uint2 u = *(const uint2*)(p0 + ((size_t)p << 14));
    s0 += bf2f(u.x & 0xffffu); s1 += bf2f(u.x >> 16);
    s2 += bf2f(u.y & 0xffffu); s3 += bf2f(u.y >> 16);
  }
#pragma unroll
  for (int msk = 1; msk < 8; msk <<= 1) {
    s0 += __shfl_xor(s0, msk); s1 += __shfl_xor(s1, msk);
    s2 += __shfl_xor(s2, msk); s3 += __shfl_xor(s3, msk);
  }
  if (chunk == 0) {
    f32x4 r; r[0] = s0; r[1] = s1; r[2] = s2; r[3] = s3;
    *(f32x4*)(kvf + (qid << 2)) = r;
  }
}

// ---------------- pass B1: M1T[b][o][j=h*64+d] = sum_e kv[d][e]/S * wo[o][h*64+e] ----
__global__ __launch_bounds__(256, 2)
void gka_m1(const float* __restrict__ kvf, const float* __restrict__ wo,
            unsigned short* __restrict__ m1t) {
  const int tid = threadIdx.x;
  const int lane = tid & 63;
  const int wid = tid >> 6;               // wave -> o-range
  const int l15 = lane & 15, l4 = lane >> 4;
  const int blk = blockIdx.x;             // 16 = 4b x 4h
  const int b = blk >> 2, h = blk & 3;
  const float invS = 1.f / (float)SEQ;
  const float* kvh = kvf + ((b * 4 + h) << 12);

  f32x4 acc[4][4];
#pragma unroll
  for (int m = 0; m < 4; ++m)
#pragma unroll
    for (int n = 0; n < 4; ++n) acc[m][n] = (f32x4)0.0f;

#pragma unroll
  for (int kk = 0; kk < 2; ++kk) {        // K = 64 (e)
    bf16x8 af[4], bw[4];
#pragma unroll
    for (int m = 0; m < 4; ++m) {
      // gather (d = m*16+l15, e = kk*32+l4*8+j) from fragment layout
      int base = (m * 4 + kk * 2 + (l4 >> 1)) * 256 +
                 ((l15 >> 2) * 16 + (l4 & 1) * 8) * 4 + (l15 & 3);
      bf16x8 v;
#pragma unroll
      for (int j = 0; j < 8; ++j) v[j] = f2bf(kvh[base + j * 4] * invS);
      af[m] = v;
    }
#pragma unroll
    for (int n = 0; n < 4; ++n) {
      int o = wid * 64 + n * 16 + l15;
      const f32x4* wp = (const f32x4*)(wo + (size_t)o * 256 + h * 64 + kk * 32 + l4 * 8);
      f32x4 w0 = wp[0], w1 = wp[1];
      bf16x8 v;
      v[0] = f2bf(w0[0]); v[1] = f2bf(w0[1]); v[2] = f2bf(w0[2]); v[3] = f2bf(w0[3]);
      v[4] = f2bf(w1[0]); v[5] = f2bf(w1[1]); v[6] = f2bf(w1[2]); v[7] = f2bf(w1[3]);
      bw[n] = v;
    }
#pragma unroll
    for (int m = 0; m < 4; ++m)
#pragma unroll
      for (int n = 0; n < 4; ++n)
        acc[m][n] = MFMA16(af[m], bw[n], acc[m][n]);
  }
#pragma unroll
  for (int m = 0; m < 4; ++m)
#pragma unroll
    for (int n = 0; n < 4; ++n) {
      int o = wid * 64 + n * 16 + l15;
      int j0 = h * 64 + m * 16 + l4 * 4;
      bf16x4 pk;
#pragma unroll
      for (int r = 0; r < 4; ++r) pk[r] = f2bf(acc[m][n][r]);
      *(bf16x4*)(m1t + (size_t)(b * 256 + o) * 256 + j0) = pk;
    }
}

// ---------------- pass B2: wcf = fragment-major WcT; Wc[i][o] = sum_j wqT[i][j]*M1T[o][j]
__global__ __launch_bounds__(512, 2)
void gka_wc(const unsigned short* __restrict__ wqt, const unsigned short* __restrict__ m1t,
            unsigned short* __restrict__ wcf) {
  const int tid = threadIdx.x;
  const int lane = tid & 63;
  const int wid = tid >> 6;               // 8 waves: 2M x 4N
  const int wm = wid >> 2, wn = wid & 3;
  const int l15 = lane & 15, l4 = lane >> 4;
  const int blk = blockIdx.x;             // 8 = 4b x 2 i-half
  const int b = blk >> 1, ih = blk & 1;

  f32x4 acc[4][4];
#pragma unroll
  for (int m = 0; m < 4; ++m)
#pragma unroll
    for (int n = 0; n < 4; ++n) acc[m][n] = (f32x4)0.0f;

#pragma unroll
  for (int kk = 0; kk < 8; ++kk) {        // K = 256 (j)
    bf16x8 af[4], bw[4];
#pragma unroll
    for (int m = 0; m < 4; ++m) {
      int i = ih * 128 + wm * 64 + m * 16 + l15;
      af[m] = *(const bf16x8*)(wqt + i * 256 + kk * 32 + l4 * 8);
    }
#pragma unroll
    for (int n = 0; n < 4; ++n) {
      int o = wn * 64 + n * 16 + l15;
      bw[n] = *(const bf16x8*)(m1t + (size_t)(b * 256 + o) * 256 + kk * 32 + l4 * 8);
    }
#pragma unroll
    for (int m = 0; m < 4; ++m)
#pragma unroll
      for (int n = 0; n < 4; ++n)
        acc[m][n] = MFMA16(af[m], bw[n], acc[m][n]);
  }
  // store to fragment-major wcf for gka_out
#pragma unroll
  for (int m = 0; m < 4; ++m)
#pragma unroll
    for (int n = 0; n < 4; ++n) {
      int kko = ih * 4 + wm * 2 + (m >> 1);
      int laneo = ((m & 1) * 2 + (l4 >> 1)) * 16 + l15;
      int jo = (l4 & 1) * 4;
      bf16x4 pk;
#pragma unroll
      for (int r = 0; r < 4; ++r) pk[r] = f2bf(acc[m][n][r]);
      *(bf16x4*)(wcf + ((size_t)b << 16) +
                 (((((wn * 8 + kko) * 4 + n) * 64) + laneo) << 3) + jo) = pk;
    }
}

// ---------------- pass C: out = seq @ Wc[b] + bo  (1024 x 32-token tiles, LDS) -------
__global__ __launch_bounds__(256, 4)
void gka_out(const float* __restrict__ seq, const unsigned short* __restrict__ wcf,
             const float* __restrict__ bo, float* __restrict__ out) {
  __shared__ char smem[16384];
  const int tid = threadIdx.x;
  const int lane = tid & 63;
  const int wid = tid >> 6;               // wave -> o-range (64 cols)
  const int l15 = lane & 15, l4 = lane >> 4, l7 = lane & 7;
  const int tile = blockIdx.x;            // 1024 = 4b x 256 tiles of 32 rows
  const int b = tile >> 8;
  const int srow = (tile & 255) * 32;

  stage_x<32>(smem, seq + (size_t)(b * SEQ + srow) * EMBED, tid);

  const unsigned short* Wf = wcf + ((size_t)b << 16);
  float bov[4];
#pragma unroll
  for (int n = 0; n < 4; ++n) bov[n] = bo[wid * 64 + n * 16 + l15];

  f32x4 acc[2][4];
#pragma unroll
  for (int m = 0; m < 2; ++m)
#pragma unroll
    for (int n = 0; n < 4; ++n) acc[m][n] = (f32x4)0.0f;

  __syncthreads();

#pragma unroll
  for (int kk = 0; kk < 8; ++kk) {        // K = 256, no barriers
    bf16x8 af[2], bw[4];
#pragma unroll
    for (int m = 0; m < 2; ++m) {
      int row = m * 16 + l15;
      af[m] = *(const bf16x8*)(smem + row * 512 + ((kk * 64 + l4 * 16) ^ (l7 << 4)));
    }
#pragma unroll
    for (int n = 0; n < 4; ++n)           // coalesced 512B per wave, L2-resident
      bw[n] = *(const bf16x8*)(Wf + ((((wid * 8 + kk) * 4 + n) * 64 + lane) << 3));
#pragma unroll
    for (int m = 0; m < 2; ++m)
#pragma unroll
      for (int n = 0; n < 4; ++n)
        acc[m][n] = MFMA16(af[m], bw[n], acc[m][n]);
  }

  float* dst = out + (size_t)(b * SEQ + srow) * EMBED;
#pragma unroll
  for (int m = 0; m < 2; ++m)
#pragma unroll
    for (int n = 0; n < 4; ++n)
#pragma unroll
      for (int r = 0; r < 4; ++r)
        dst[(size_t)(m * 16 + l4 * 4 + r) * EMBED + wid * 64 + n * 16 + l15] =
            acc[m][n][r] + bov[n];
}

extern "C" void kernel_launch(void* const* d_in, const int* in_sizes, int n_in,
                              void* d_out, int out_size, void* d_ws, size_t ws_size,
                              hipStream_t stream) {
  const float* seq = (const float*)d_in[0];
  const float* wq  = (const float*)d_in[1];
  const float* wk  = (const float*)d_in[2];
  const float* wv  = (const float*)d_in[3];
  const float* wo  = (const float*)d_in[4];
  const float* bo  = (const float*)d_in[5];
  const float* lkg = (const float*)d_in[6];
  const float* lkb = (const float*)d_in[7];
  const float* lvg = (const float*)d_in[8];
  const float* lvb = (const float*)d_in[9];
  float* out = (float*)d_out;
  char* ws = (char*)d_ws;

  unsigned short* wkf = (unsigned short*)(ws + 0);
  unsigned short* wvf = (unsigned short*)(ws + 131072);
  unsigned short* wqt = (unsigned short*)(ws + 262144);
  float*          kvf = (float*)(ws + 524288);
  unsigned short* m1t = (unsigned short*)(ws + 786432);
  unsigned short* wcf = (unsigned short*)(ws + 1310720);
  unsigned short* P   = (unsigned short*)d_out;   // 16.8MB partials, overwritten by gka_out

  gka_prep<<<80, 256, 0, stream>>>(wq, wk, wv, wkf, wvf, wqt);
  gka_kv<<<512, 256, 0, stream>>>(seq, wkf, wvf, lkg, lkb, lvg, lvb, P);
  gka_red<<<512, 256, 0, stream>>>(P, kvf);
  gka_m1<<<16, 256, 0, stream>>>(kvf, wo, m1t);
  gka_wc<<<8, 512, 0, stream>>>(wqt, m1t, wcf);
  gka_out<<<1024, 256, 0, stream>>>(seq, wcf, bo, out);
}

// Round 6
// 67.386 us; speedup vs baseline: 1.2303x; 1.0907x over previous
//
#include <hip/hip_runtime.h>
#include <hip/hip_bf16.h>
#include <stdint.h>

// Galerkin self-attention, fused:
//   out = seq @ (wq.T @ blockdiag_h(kv[b,h]) @ wo.T) + bo
//   kv[b,h] = (1/S) * LN(k)_h^T @ LN(v)_h,   k = seq@wk.T, v = seq@wv.T
// v6: gka_m1 folded into gka_wc (M1T computed into 64KB swizzled LDS per
//     o-half block; m1t global round-trip and one kernel launch removed).
//     kv / red / prep / out unchanged from v5.
// ws layout (bytes):
//   0        wkf bf16 fragment-major [wid][kk][n][lane][8]
//   131072   wvf bf16 fragment-major
//   262144   wqT bf16 [256 i][256 j]
//   524288   kvf f32 [4 b][4 h][4096 frag]   (fragment order, by gka_red)
//   1310720  wcf bf16 fragment-major [b][o6][kk][n][lane][8]
// d_out doubles as scratch for P = bf16 partials [4 b][128 p][4 h][4096 frag]
// (16.8MB of the 33.5MB output buffer); gka_out fully overwrites d_out last.

#define EMBED 256
#define SEQ   8192
#define LN_EPS 1e-5f

using bf16x8 = __attribute__((ext_vector_type(8))) short;
using bf16x4 = __attribute__((ext_vector_type(4))) short;
using f32x4  = __attribute__((ext_vector_type(4))) float;

static __device__ __forceinline__ short f2bf(float f) {
  __hip_bfloat16 h = __float2bfloat16(f);
  return __builtin_bit_cast(short, h);
}
static __device__ __forceinline__ float bf2f(uint32_t u) {
  return __uint_as_float(u << 16);
}

#define MFMA16(a, b, c) __builtin_amdgcn_mfma_f32_16x16x32_bf16((a), (b), (c), 0, 0, 0)

// Stage ROWS x 256 fp32 rows -> bf16 LDS [ROWS][256], rows 512B, byte^=(row&7)<<4
template <int ROWS>
static __device__ __forceinline__ void stage_x(char* smem, const float* __restrict__ src, int tid) {
#pragma unroll
  for (int i = 0; i < ROWS / 8; ++i) {
    int g = tid + i * 256;              // 16B-granule index
    int row = g >> 5, c16 = g & 31;
    const f32x4* p = (const f32x4*)(src + row * EMBED + c16 * 8);
    f32x4 f0 = p[0], f1 = p[1];
    bf16x8 v;
    v[0] = f2bf(f0[0]); v[1] = f2bf(f0[1]); v[2] = f2bf(f0[2]); v[3] = f2bf(f0[3]);
    v[4] = f2bf(f1[0]); v[5] = f2bf(f1[1]); v[6] = f2bf(f1[2]); v[7] = f2bf(f1[3]);
    *(bf16x8*)(smem + row * 512 + ((c16 * 16) ^ ((row & 7) << 4))) = v;
  }
}

// ---------------- prep: wk/wv -> fragment-major bf16; wq -> wqT (tile transpose) -----
__global__ void gka_prep(const float* __restrict__ wq, const float* __restrict__ wk,
                         const float* __restrict__ wv,
                         unsigned short* __restrict__ wkf, unsigned short* __restrict__ wvf,
                         unsigned short* __restrict__ wqt) {
  __shared__ unsigned short T[64 * 66];
  int blk = blockIdx.x, tid = threadIdx.x;
  if (blk < 64) {                         // wk/wv -> fragment-major bf16x8 per thread
    int g = (blk & 31) * 256 + tid;       // [0, 8192)
    const float* W = (blk < 32) ? wk : wv;
    unsigned short* D = (blk < 32) ? wkf : wvf;
    int wid = g >> 11, kk = (g >> 8) & 7, n = (g >> 6) & 3, ln = g & 63;
    int row = wid * 64 + n * 16 + (ln & 15);
    int c0 = kk * 32 + (ln >> 4) * 8;
    const f32x4* p = (const f32x4*)(W + row * 256 + c0);
    f32x4 f0 = p[0], f1 = p[1];
    bf16x8 v;
    v[0] = f2bf(f0[0]); v[1] = f2bf(f0[1]); v[2] = f2bf(f0[2]); v[3] = f2bf(f0[3]);
    v[4] = f2bf(f1[0]); v[5] = f2bf(f1[1]); v[6] = f2bf(f1[2]); v[7] = f2bf(f1[3]);
    *(bf16x8*)(D + g * 8) = v;
    return;
  }
  // 16 blocks: 64x64 tile transpose wqt[i][j] = wq[j][i], coalesced both sides
  int t = blk - 64, ti = t >> 2, tj = t & 3;
#pragma unroll
  for (int it = 0; it < 4; ++it) {
    int g = tid + it * 256;               // 1024 granules of 4 floats
    int jl = g >> 4, g4 = g & 15;
    f32x4 f = *(const f32x4*)(wq + (tj * 64 + jl) * 256 + ti * 64 + g4 * 4);
#pragma unroll
    for (int q = 0; q < 4; ++q) T[jl * 66 + g4 * 4 + q] = (unsigned short)f2bf(f[q]);
  }
  __syncthreads();
#pragma unroll
  for (int it = 0; it < 2; ++it) {
    int g = tid + it * 256;               // 512 output groups of 8
    int il = g >> 3, j8 = g & 7;
    bf16x8 v;
#pragma unroll
    for (int q = 0; q < 8; ++q) v[q] = (short)T[(j8 * 8 + q) * 66 + il];
    *(bf16x8*)(wqt + (ti * 64 + il) * 256 + tj * 64 + j8 * 8) = v;
  }
}

// ---------------- pass A: k,v GEMM (merged) + per-head LN + per-tile kv partial ------
__global__ __launch_bounds__(256, 2)
void gka_kv(const float* __restrict__ seq,
            const unsigned short* __restrict__ wkf, const unsigned short* __restrict__ wvf,
            const float* __restrict__ lkg, const float* __restrict__ lkb,
            const float* __restrict__ lvg, const float* __restrict__ lvb,
            unsigned short* __restrict__ P) {
  __shared__ char smem[65536];            // [0,32K): x, later vT; [32K,64K): kT
  const int tid = threadIdx.x;
  const int lane = tid & 63;
  const int wid = tid >> 6;               // wave = head
  const int l15 = lane & 15, l4 = lane >> 4, l7 = lane & 7;
  const int tile = blockIdx.x;            // 512 blocks, 64 tokens each
  const int b = tile >> 7;
  const int ptile = tile & 127;

  stage_x<64>(smem, seq + (size_t)(b * SEQ + ptile * 64) * EMBED, tid);
  __syncthreads();

  // merged k+v GEMM: one pass over x, both weight streams
  f32x4 acck[4][4], accv[4][4];
#pragma unroll
  for (int m = 0; m < 4; ++m)
#pragma unroll
    for (int n = 0; n < 4; ++n) { acck[m][n] = (f32x4)0.0f; accv[m][n] = (f32x4)0.0f; }

#pragma unroll
  for (int kk = 0; kk < 8; ++kk) {        // K = 256, steps of 32
    bf16x8 af[4], bwk[4], bwv[4];
#pragma unroll
    for (int m = 0; m < 4; ++m) {
      int row = m * 16 + l15;
      af[m] = *(const bf16x8*)(smem + row * 512 + ((kk * 64 + l4 * 16) ^ (l7 << 4)));
    }
#pragma unroll
    for (int n = 0; n < 4; ++n) {         // fragment-major: 512B coalesced per wave
      size_t off = (((wid * 8 + kk) * 4 + n) * 64 + lane) << 3;
      bwk[n] = *(const bf16x8*)(wkf + off);
      bwv[n] = *(const bf16x8*)(wvf + off);
    }
#pragma unroll
    for (int m = 0; m < 4; ++m)
#pragma unroll
      for (int n = 0; n < 4; ++n) {
        acck[m][n] = MFMA16(af[m], bwk[n], acck[m][n]);
        accv[m][n] = MFMA16(af[m], bwv[n], accv[m][n]);
      }
  }

  __syncthreads();                        // all x-tile LDS reads done

  // LN over this wave's 64 head-cols; write kT -> smem+32K, vT -> smem (over x)
#pragma unroll
  for (int mat = 0; mat < 2; ++mat) {
    const f32x4 (*acc)[4] = mat ? accv : acck;     // mat is unroll-static
    const float* gp = mat ? lvg : lkg;
    const float* bp = mat ? lvb : lkb;
    float gv[4], bv[4];
#pragma unroll
    for (int n = 0; n < 4; ++n) { gv[n] = gp[n * 16 + l15]; bv[n] = bp[n * 16 + l15]; }
    char* T = smem + (mat ? 0 : 32768) + wid * 8192;  // [64 d|e][64 s] bf16, 128B rows
#pragma unroll
    for (int m = 0; m < 4; ++m) {
      float mu[4], rs[4];
#pragma unroll
      for (int r = 0; r < 4; ++r) {
        float s1 = 0.f, s2 = 0.f;
#pragma unroll
        for (int n = 0; n < 4; ++n) { float x = acc[m][n][r]; s1 += x; s2 += x * x; }
#pragma unroll
        for (int msk = 1; msk < 16; msk <<= 1) {
          s1 += __shfl_xor(s1, msk);
          s2 += __shfl_xor(s2, msk);
        }
        mu[r] = s1 * (1.f / 64.f);
        float var = s2 * (1.f / 64.f) - mu[r] * mu[r];
        rs[r] = rsqrtf(var + LN_EPS);
      }
#pragma unroll
      for (int n = 0; n < 4; ++n) {
        bf16x4 pk;
#pragma unroll
        for (int r = 0; r < 4; ++r)
          pk[r] = f2bf((acc[m][n][r] - mu[r]) * rs[r] * gv[n] + bv[n]);
        int d = n * 16 + l15;             // d&7 == l7
        int sb = m * 32 + l4 * 8;         // byte offset of s0 = m*16+l4*4
        *(bf16x4*)(T + d * 128 + (sb ^ (l7 << 4))) = pk;
      }
    }
  }

  __syncthreads();                        // kT + vT ready

  // kv outer product: wave = head; kv[d][e] += sum_s kT[d][s] * vT[e][s]
  f32x4 a2[4][4];
#pragma unroll
  for (int fd = 0; fd < 4; ++fd)
#pragma unroll
    for (int n = 0; n < 4; ++n) a2[fd][n] = (f32x4)0.0f;

#pragma unroll
  for (int kk = 0; kk < 2; ++kk) {        // 64 tokens = 2 K-steps
    bf16x8 ak[4], bv2[4];
#pragma unroll
    for (int fd = 0; fd < 4; ++fd) {
      int d = fd * 16 + l15;
      ak[fd] = *(const bf16x8*)(smem + 32768 + wid * 8192 + d * 128 +
                                ((kk * 64 + l4 * 16) ^ (l7 << 4)));
    }
#pragma unroll
    for (int n = 0; n < 4; ++n) {
      int e = n * 16 + l15;
      bv2[n] = *(const bf16x8*)(smem + wid * 8192 + e * 128 +
                                ((kk * 64 + l4 * 16) ^ (l7 << 4)));
    }
#pragma unroll
    for (int fd = 0; fd < 4; ++fd)
#pragma unroll
      for (int n = 0; n < 4; ++n)
        a2[fd][n] = MFMA16(ak[fd], bv2[n], a2[fd][n]);
  }

  // store P in raw fragment order: flat = (fd*4+n)*256 + lane*4 + r  (coalesced 512B)
  unsigned short* Ph = P + ((size_t)((b * 128 + ptile) * 4 + wid) << 12);
#pragma unroll
  for (int fd = 0; fd < 4; ++fd)
#pragma unroll
    for (int n = 0; n < 4; ++n) {
      bf16x4 pk;
#pragma unroll
      for (int r = 0; r < 4; ++r) pk[r] = f2bf(a2[fd][n][r]);
      *(bf16x4*)(Ph + (fd * 4 + n) * 256 + lane * 4) = pk;
    }
}

// ---------------- reduce: kvf[b,h,flat] = sum_p P[b,p,h,flat]  (layout-agnostic) -----
__global__ __launch_bounds__(256)
void gka_red(const unsigned short* __restrict__ P, float* __restrict__ kvf) {
  int gtid = blockIdx.x * 256 + threadIdx.x;  // 131072 = 16384 quads x 8 chunks
  int chunk = gtid & 7;
  int qid = gtid >> 3;                        // (b<<12) | (h<<10) | t4
  int b = qid >> 12, h = (qid >> 10) & 3, t4 = qid & 1023;
  const unsigned short* p0 = P + ((size_t)(b * 512 + h) << 12) + t4 * 4;
  float s0 = 0.f, s1 = 0.f, s2 = 0.f, s3 = 0.f;
#pragma unroll
  for (int s = 0; s < 16; ++s) {
    int p = chunk * 16 + s;
    uint2 u = *(const uint2*)(p0 + ((size_t)p << 14));
    s0 += bf2f(u.x & 0xffffu); s1 += bf2f(u.x >> 16);
    s2 += bf2f(u.y & 0xffffu); s3 += bf2f(u.y >> 16);
  }
#pragma unroll
  for (int msk = 1; msk < 8; msk <<= 1) {
    s0 += __shfl_xor(s0, msk); s1 += __shfl_xor(s1, msk);
    s2 += __shfl_xor(s2, msk); s3 += __shfl_xor(s3, msk);
  }
  if (chunk == 0) {
    f32x4 r; r[0] = s0; r[1] = s1; r[2] = s2; r[3] = s3;
    *(f32x4*)(kvf + (qid << 2)) = r;
  }
}

// ---------------- pass B (merged m1+wc): per (b, o-half) block ----------------------
// phase 1: M1T[o_loc][j=h*64+d] = sum_e kv[b,h,d,e]/S * wo[o][h*64+e]  -> LDS (swz)
// phase 2: WcT frag-major: Wc[i][o] = sum_j wqT[i][j] * M1T[o_loc][j]
__global__ __launch_bounds__(512)
void gka_wc(const float* __restrict__ kvf, const float* __restrict__ wo,
            const unsigned short* __restrict__ wqt, unsigned short* __restrict__ wcf) {
  __shared__ char M1[65536];              // [128 o_loc][256 j] bf16, 512B rows, swz
  const int tid = threadIdx.x;
  const int lane = tid & 63;
  const int wid = tid >> 6;               // 8 waves
  const int l15 = lane & 15, l4 = lane >> 4;
  const int blk = blockIdx.x;             // 8 = 4b x 2 o-half
  const int b = blk >> 1, oh = blk & 1;
  const float invS = 1.f / (float)SEQ;

  // ---- phase 1: wave -> (wo_t = wid>>2 o-64-range, wj = wid&3 head) ----
  {
    const int wo_t = wid >> 2, wj = wid & 3;
    const float* kvh = kvf + ((b * 4 + wj) << 12);
    f32x4 acc[4][4];
#pragma unroll
    for (int m = 0; m < 4; ++m)
#pragma unroll
      for (int n = 0; n < 4; ++n) acc[m][n] = (f32x4)0.0f;

#pragma unroll
    for (int kk = 0; kk < 2; ++kk) {      // K = 64 (e)
      bf16x8 af[4], bw[4];
#pragma unroll
      for (int m = 0; m < 4; ++m) {
        // gather (d = m*16+l15, e = kk*32+l4*8+j) from kv fragment layout
        int base = (m * 4 + kk * 2 + (l4 >> 1)) * 256 +
                   ((l15 >> 2) * 16 + (l4 & 1) * 8) * 4 + (l15 & 3);
        bf16x8 v;
#pragma unroll
        for (int j = 0; j < 8; ++j) v[j] = f2bf(kvh[base + j * 4] * invS);
        af[m] = v;
      }
#pragma unroll
      for (int n = 0; n < 4; ++n) {
        int o = oh * 128 + wo_t * 64 + n * 16 + l15;
        const f32x4* wp = (const f32x4*)(wo + (size_t)o * 256 + wj * 64 + kk * 32 + l4 * 8);
        f32x4 w0 = wp[0], w1 = wp[1];
        bf16x8 v;
        v[0] = f2bf(w0[0]); v[1] = f2bf(w0[1]); v[2] = f2bf(w0[2]); v[3] = f2bf(w0[3]);
        v[4] = f2bf(w1[0]); v[5] = f2bf(w1[1]); v[6] = f2bf(w1[2]); v[7] = f2bf(w1[3]);
        bw[n] = v;
      }
#pragma unroll
      for (int m = 0; m < 4; ++m)
#pragma unroll
        for (int n = 0; n < 4; ++n)
          acc[m][n] = MFMA16(af[m], bw[n], acc[m][n]);
    }
    // store to LDS M1T: row = o_loc, col j = wj*64 + m*16 + l4*4 + r (bf16x4), swz
#pragma unroll
    for (int m = 0; m < 4; ++m)
#pragma unroll
      for (int n = 0; n < 4; ++n) {
        int row = wo_t * 64 + n * 16 + l15;
        int jb = (wj * 64 + m * 16 + l4 * 4) * 2;
        bf16x4 pk;
#pragma unroll
        for (int r = 0; r < 4; ++r) pk[r] = f2bf(acc[m][n][r]);
        *(bf16x4*)(M1 + row * 512 + (jb ^ ((row & 7) << 4))) = pk;
      }
  }

  __syncthreads();

  // ---- phase 2: wave -> (wi = wid>>1 i-64-range, wo2 = wid&1 o-64-range) ----
  {
    const int wi = wid >> 1, wo2 = wid & 1;
    f32x4 acc[4][4];
#pragma unroll
    for (int m = 0; m < 4; ++m)
#pragma unroll
      for (int n = 0; n < 4; ++n) acc[m][n] = (f32x4)0.0f;

#pragma unroll
    for (int kk = 0; kk < 8; ++kk) {      // K = 256 (j)
      bf16x8 af[4], bw[4];
#pragma unroll
      for (int m = 0; m < 4; ++m) {
        int i = wi * 64 + m * 16 + l15;
        af[m] = *(const bf16x8*)(wqt + i * 256 + kk * 32 + l4 * 8);
      }
#pragma unroll
      for (int n = 0; n < 4; ++n) {
        int row = wo2 * 64 + n * 16 + l15;
        bw[n] = *(const bf16x8*)(M1 + row * 512 +
                                 ((kk * 64 + l4 * 16) ^ ((row & 7) << 4)));
      }
#pragma unroll
      for (int m = 0; m < 4; ++m)
#pragma unroll
        for (int n = 0; n < 4; ++n)
          acc[m][n] = MFMA16(af[m], bw[n], acc[m][n]);
    }
    // store to fragment-major wcf for gka_out
    const int o6 = oh * 2 + wo2;
#pragma unroll
    for (int m = 0; m < 4; ++m)
#pragma unroll
      for (int n = 0; n < 4; ++n) {
        int kko = wi * 2 + (m >> 1);
        int laneo = ((m & 1) * 2 + (l4 >> 1)) * 16 + l15;
        int jo = (l4 & 1) * 4;
        bf16x4 pk;
#pragma unroll
        for (int r = 0; r < 4; ++r) pk[r] = f2bf(acc[m][n][r]);
        *(bf16x4*)(wcf + ((size_t)b << 16) +
                   (((((o6 * 8 + kko) * 4 + n) * 64) + laneo) << 3) + jo) = pk;
      }
  }
}

// ---------------- pass C: out = seq @ Wc[b] + bo  (1024 x 32-token tiles, LDS) -------
__global__ __launch_bounds__(256, 4)
void gka_out(const float* __restrict__ seq, const unsigned short* __restrict__ wcf,
             const float* __restrict__ bo, float* __restrict__ out) {
  __shared__ char smem[16384];
  const int tid = threadIdx.x;
  const int lane = tid & 63;
  const int wid = tid >> 6;               // wave -> o-range (64 cols)
  const int l15 = lane & 15, l4 = lane >> 4, l7 = lane & 7;
  const int tile = blockIdx.x;            // 1024 = 4b x 256 tiles of 32 rows
  const int b = tile >> 8;
  const int srow = (tile & 255) * 32;

  stage_x<32>(smem, seq + (size_t)(b * SEQ + srow) * EMBED, tid);

  const unsigned short* Wf = wcf + ((size_t)b << 16);
  float bov[4];
#pragma unroll
  for (int n = 0; n < 4; ++n) bov[n] = bo[wid * 64 + n * 16 + l15];

  f32x4 acc[2][4];
#pragma unroll
  for (int m = 0; m < 2; ++m)
#pragma unroll
    for (int n = 0; n < 4; ++n) acc[m][n] = (f32x4)0.0f;

  __syncthreads();

#pragma unroll
  for (int kk = 0; kk < 8; ++kk) {        // K = 256, no barriers
    bf16x8 af[2], bw[4];
#pragma unroll
    for (int m = 0; m < 2; ++m) {
      int row = m * 16 + l15;
      af[m] = *(const bf16x8*)(smem + row * 512 + ((kk * 64 + l4 * 16) ^ (l7 << 4)));
    }
#pragma unroll
    for (int n = 0; n < 4; ++n)           // coalesced 512B per wave, L2-resident
      bw[n] = *(const bf16x8*)(Wf + ((((wid * 8 + kk) * 4 + n) * 64 + lane) << 3));
#pragma unroll
    for (int m = 0; m < 2; ++m)
#pragma unroll
      for (int n = 0; n < 4; ++n)
        acc[m][n] = MFMA16(af[m], bw[n], acc[m][n]);
  }

  float* dst = out + (size_t)(b * SEQ + srow) * EMBED;
#pragma unroll
  for (int m = 0; m < 2; ++m)
#pragma unroll
    for (int n = 0; n < 4; ++n)
#pragma unroll
      for (int r = 0; r < 4; ++r)
        dst[(size_t)(m * 16 + l4 * 4 + r) * EMBED + wid * 64 + n * 16 + l15] =
            acc[m][n][r] + bov[n];
}

extern "C" void kernel_launch(void* const* d_in, const int* in_sizes, int n_in,
                              void* d_out, int out_size, void* d_ws, size_t ws_size,
                              hipStream_t stream) {
  const float* seq = (const float*)d_in[0];
  const float* wq  = (const float*)d_in[1];
  const float* wk  = (const float*)d_in[2];
  const float* wv  = (const float*)d_in[3];
  const float* wo  = (const float*)d_in[4];
  const float* bo  = (const float*)d_in[5];
  const float* lkg = (const float*)d_in[6];
  const float* lkb = (const float*)d_in[7];
  const float* lvg = (const float*)d_in[8];
  const float* lvb = (const float*)d_in[9];
  float* out = (float*)d_out;
  char* ws = (char*)d_ws;

  unsigned short* wkf = (unsigned short*)(ws + 0);
  unsigned short* wvf = (unsigned short*)(ws + 131072);
  unsigned short* wqt = (unsigned short*)(ws + 262144);
  float*          kvf = (float*)(ws + 524288);
  unsigned short* wcf = (unsigned short*)(ws + 1310720);
  unsigned short* P   = (unsigned short*)d_out;   // 16.8MB partials, overwritten by gka_out

  gka_prep<<<80, 256, 0, stream>>>(wq, wk, wv, wkf, wvf, wqt);
  gka_kv<<<512, 256, 0, stream>>>(seq, wkf, wvf, lkg, lkb, lvg, lvb, P);
  gka_red<<<512, 256, 0, stream>>>(P, kvf);
  gka_wc<<<8, 512, 0, stream>>>(kvf, wo, wqt, wcf);
  gka_out<<<1024, 256, 0, stream>>>(seq, wcf, bo, out);
}